// Round 7
// baseline (78.876 us; speedup 1.0000x reference)
//
#include <hip/hip_runtime.h>

#define N_LC 4194304
#define T_STEPS 20
#define BLOCK 256
#define VEC 8                         // floats per thread (2x float4 chains)
#define GRID (N_LC / (BLOCK * VEC))   // 2048 blocks

// Resident fraction: blocks with (blockIdx.x % 32) < 19 use cache-allocating
// loads for noise (19/32 * 335.5MB = 199MB + 50MB states = 249MB < 256MB L3);
// the rest stream nontemporally from HBM.
#define RES_MOD 32
#define RES_CUT 19

typedef float vfloat4 __attribute__((ext_vector_type(4)));

__device__ __forceinline__ vfloat4 ld4(const float* p) {
    return *reinterpret_cast<const vfloat4*>(p);
}
__device__ __forceinline__ vfloat4 ld4nt(const float* p) {
    return __builtin_nontemporal_load(reinterpret_cast<const vfloat4*>(p));
}

// ---------------------------------------------------------------------------
// Sim kernel: 8 neurons/thread, two independent float4 chains for MLP.
// __launch_bounds__(256,4): VGPR cap 128 (live set ~60 -> no spill, but stops
// unbounded load hoisting). FMA-minimized Izhikevich body (~12 VALU/step):
//   v' = fma(v, fma(0.04,v,6), w),  w = fma(0.5,n,140+Iconst) - u
// Block partial sums -> ws[blockIdx.x]; no atomics, no memset.
// ---------------------------------------------------------------------------
template <bool RESIDENT>
__device__ __forceinline__ void sim_body(
    const float* __restrict__ amygdala,
    const float* __restrict__ insula,
    const float* __restrict__ circadian,
    const float* __restrict__ cms,
    const float* __restrict__ v0,
    const float* __restrict__ u0,
    const float* __restrict__ rate0,
    const float* __restrict__ noise,
    float* __restrict__ ws_partial)
{
    const size_t base = (size_t)(blockIdx.x * BLOCK + threadIdx.x) * VEC;

    const float tonic  = 2.0f + circadian[0] * 3.0f + insula[0] * 5.0f + cms[0] * 3.0f;
    const float phasic = (amygdala[0] > 0.3f) ? 15.0f : 0.0f;
    const float Iconst140 = tonic + phasic + 0.5f + 140.0f;   // I + 140 folded

    float v[VEC], u[VEC], r[VEC];
    {
        const vfloat4 va = ld4(v0 + base),    vb = ld4(v0 + base + 4);
        const vfloat4 ua = ld4(u0 + base),    ub = ld4(u0 + base + 4);
        const vfloat4 ra = ld4(rate0 + base), rb = ld4(rate0 + base + 4);
        #pragma unroll
        for (int i = 0; i < 4; ++i) {
            v[i] = va[i]; v[i + 4] = vb[i];
            u[i] = ua[i]; u[i + 4] = ub[i];
            r[i] = ra[i]; r[i + 4] = rb[i];
        }
    }

    #pragma unroll
    for (int t = 0; t < T_STEPS; ++t) {
        const float* p = noise + (size_t)t * N_LC + base;
        const vfloat4 na = RESIDENT ? ld4(p)     : ld4nt(p);
        const vfloat4 nb = RESIDENT ? ld4(p + 4) : ld4nt(p + 4);

        float n[VEC];
        #pragma unroll
        for (int i = 0; i < 4; ++i) { n[i] = na[i]; n[i + 4] = nb[i]; }

        #pragma unroll
        for (int i = 0; i < VEC; ++i) {
            float vv = v[i], uu = u[i];
            const float w = fmaf(0.5f, n[i], Iconst140) - uu;      // 140+I-u
            vv = fmaf(vv, fmaf(0.04f, vv, 6.0f), w);               // 0.04v^2+6v+w
            uu = fmaf(0.02f, fmaf(0.2f, vv, -uu), uu);             // u += a(bv-u)
            const bool sp = (vv >= 30.0f);
            v[i] = sp ? -65.0f : vv;
            u[i] = sp ? (uu + 8.0f) : uu;
            r[i] = fmaf(0.9f, r[i], sp ? 0.1f : 0.0f);
        }
    }

    float rsum = 0.0f;
    #pragma unroll
    for (int i = 0; i < VEC; ++i) rsum += r[i];

    #pragma unroll
    for (int off = 32; off > 0; off >>= 1)
        rsum += __shfl_down(rsum, off, 64);

    __shared__ float wave_sum[BLOCK / 64];
    const int lane = threadIdx.x & 63;
    const int wid  = threadIdx.x >> 6;
    if (lane == 0) wave_sum[wid] = rsum;
    __syncthreads();
    if (threadIdx.x == 0) {
        float bsum = 0.0f;
        #pragma unroll
        for (int w = 0; w < BLOCK / 64; ++w) bsum += wave_sum[w];
        ws_partial[blockIdx.x] = bsum;               // every slot written every call
    }
}

__global__ __launch_bounds__(BLOCK, 4) void lc_sim_kernel(
    const float* __restrict__ amygdala,
    const float* __restrict__ insula,
    const float* __restrict__ circadian,
    const float* __restrict__ cms,
    const float* __restrict__ v0,
    const float* __restrict__ u0,
    const float* __restrict__ rate0,
    const float* __restrict__ noise,
    float* __restrict__ ws_partial)
{
    if ((blockIdx.x % RES_MOD) < RES_CUT) {
        sim_body<true >(amygdala, insula, circadian, cms, v0, u0, rate0, noise, ws_partial);
    } else {
        sim_body<false>(amygdala, insula, circadian, cms, v0, u0, rate0, noise, ws_partial);
    }
}

// ---------------------------------------------------------------------------
// Finalize: reduce 2048 partials (1 block of 256), then scalar NA readout.
// ---------------------------------------------------------------------------
__global__ __launch_bounds__(BLOCK) void lc_finalize_kernel(
    const float* __restrict__ ws_partial,
    const float* __restrict__ amygdala,
    float* __restrict__ out)
{
    float s = 0.0f;
    #pragma unroll
    for (int i = 0; i < GRID / BLOCK; ++i)           // 8 strided reads/thread
        s += ws_partial[i * BLOCK + threadIdx.x];

    #pragma unroll
    for (int off = 32; off > 0; off >>= 1)
        s += __shfl_down(s, off, 64);

    __shared__ float wave_sum[BLOCK / 64];
    const int lane = threadIdx.x & 63;
    const int wid  = threadIdx.x >> 6;
    if (lane == 0) wave_sum[wid] = s;
    __syncthreads();
    if (threadIdx.x == 0) {
        float total = 0.0f;
        #pragma unroll
        for (int w = 0; w < BLOCK / 64; ++w) total += wave_sum[w];

        const float lc_mean = total / (float)N_LC;
        float raw_na = fminf(fmaxf(lc_mean * 6.0f, 0.0f), 1.0f);
        if (amygdala[0] > 0.3f) raw_na = fminf(raw_na, 0.8f);
        const float na_ema = 0.85f * 0.3f + 0.15f * raw_na;
        const float na = fminf(fmaxf(na_ema, 0.05f), 0.95f);
        out[0] = na;
        out[1] = lc_mean;
        out[2] = fminf(na * 2.0f, 1.0f);
        out[3] = fminf(na * 1.5f, 1.0f);
    }
}

extern "C" void kernel_launch(void* const* d_in, const int* in_sizes, int n_in,
                              void* d_out, int out_size, void* d_ws, size_t ws_size,
                              hipStream_t stream) {
    const float* amygdala  = (const float*)d_in[0];
    const float* insula    = (const float*)d_in[1];
    const float* circadian = (const float*)d_in[2];
    const float* cms       = (const float*)d_in[3];
    const float* v0        = (const float*)d_in[4];
    const float* u0        = (const float*)d_in[5];
    const float* rate0     = (const float*)d_in[6];
    const float* noise     = (const float*)d_in[7];
    float* out             = (float*)d_out;
    float* ws_partial      = (float*)d_ws;           // GRID floats = 8 KB

    lc_sim_kernel<<<GRID, BLOCK, 0, stream>>>(
        amygdala, insula, circadian, cms, v0, u0, rate0, noise, ws_partial);

    lc_finalize_kernel<<<1, BLOCK, 0, stream>>>(ws_partial, amygdala, out);
}

// Round 8
// 71.860 us; speedup vs baseline: 1.0976x; 1.0976x over previous
//
#include <hip/hip_runtime.h>

#define N_LC 4194304
#define T_STEPS 20
#define BLOCK 256
#define VEC 4                         // floats per thread (one float4) -- R5-proven
#define GRID (N_LC / (BLOCK * VEC))   // 4096 blocks

// Resident split (R5-proven 16/32): even blocks keep noise cache-resident
// (0.5*335.5MB + 50MB states = 218MB < 256MB L3, stable across graph
// replays); odd blocks stream noise nontemporally from HBM.
typedef float vfloat4 __attribute__((ext_vector_type(4)));

__device__ __forceinline__ vfloat4 ld4(const float* p) {
    return *reinterpret_cast<const vfloat4*>(p);
}
__device__ __forceinline__ vfloat4 ld4nt(const float* p) {
    return __builtin_nontemporal_load(reinterpret_cast<const vfloat4*>(p));
}

// ---------------------------------------------------------------------------
// Sim kernel: R5 structure + FMA-minimized Izhikevich body (~12 VALU/step):
//   w  = fma(0.5,n,140+Iconst) - u
//   v' = fma(v, fma(0.04,v,6), w)
//   u' = fma(0.02, fma(0.2,v',-u), u)
// Block partial sums -> ws[blockIdx.x]; no atomics, no memset.
// ---------------------------------------------------------------------------
template <bool RESIDENT>
__device__ __forceinline__ void sim_body(
    const float* __restrict__ amygdala,
    const float* __restrict__ insula,
    const float* __restrict__ circadian,
    const float* __restrict__ cms,
    const float* __restrict__ v0,
    const float* __restrict__ u0,
    const float* __restrict__ rate0,
    const float* __restrict__ noise,
    float* __restrict__ ws_partial)
{
    const size_t base = (size_t)(blockIdx.x * BLOCK + threadIdx.x) * VEC;

    const float tonic  = 2.0f + circadian[0] * 3.0f + insula[0] * 5.0f + cms[0] * 3.0f;
    const float phasic = (amygdala[0] > 0.3f) ? 15.0f : 0.0f;
    const float Iconst140 = tonic + phasic + 0.5f + 140.0f;   // 140 + I folded

    float v[VEC], u[VEC], r[VEC];
    {
        const vfloat4 vv = ld4(v0 + base);
        const vfloat4 uu = ld4(u0 + base);
        const vfloat4 rr = ld4(rate0 + base);
        #pragma unroll
        for (int i = 0; i < VEC; ++i) { v[i] = vv[i]; u[i] = uu[i]; r[i] = rr[i]; }
    }

    #pragma unroll
    for (int t = 0; t < T_STEPS; ++t) {
        const float* p = noise + (size_t)t * N_LC + base;
        const vfloat4 nn = RESIDENT ? ld4(p) : ld4nt(p);

        #pragma unroll
        for (int i = 0; i < VEC; ++i) {
            float vv = v[i], uu = u[i];
            const float w = fmaf(0.5f, nn[i], Iconst140) - uu;     // 140+I-u
            vv = fmaf(vv, fmaf(0.04f, vv, 6.0f), w);               // 0.04v^2+6v+w
            uu = fmaf(0.02f, fmaf(0.2f, vv, -uu), uu);             // u += a(bv-u)
            const bool sp = (vv >= 30.0f);
            v[i] = sp ? -65.0f : vv;
            u[i] = sp ? (uu + 8.0f) : uu;
            r[i] = fmaf(0.9f, r[i], sp ? 0.1f : 0.0f);
        }
    }

    float rsum = (r[0] + r[1]) + (r[2] + r[3]);
    #pragma unroll
    for (int off = 32; off > 0; off >>= 1)
        rsum += __shfl_down(rsum, off, 64);

    __shared__ float wave_sum[BLOCK / 64];
    const int lane = threadIdx.x & 63;
    const int wid  = threadIdx.x >> 6;
    if (lane == 0) wave_sum[wid] = rsum;
    __syncthreads();
    if (threadIdx.x == 0) {
        float bsum = 0.0f;
        #pragma unroll
        for (int w = 0; w < BLOCK / 64; ++w) bsum += wave_sum[w];
        ws_partial[blockIdx.x] = bsum;               // every slot written every call
    }
}

__global__ __launch_bounds__(BLOCK) void lc_sim_kernel(
    const float* __restrict__ amygdala,
    const float* __restrict__ insula,
    const float* __restrict__ circadian,
    const float* __restrict__ cms,
    const float* __restrict__ v0,
    const float* __restrict__ u0,
    const float* __restrict__ rate0,
    const float* __restrict__ noise,
    float* __restrict__ ws_partial)
{
    if ((blockIdx.x & 1) == 0) {
        sim_body<true >(amygdala, insula, circadian, cms, v0, u0, rate0, noise, ws_partial);
    } else {
        sim_body<false>(amygdala, insula, circadian, cms, v0, u0, rate0, noise, ws_partial);
    }
}

// ---------------------------------------------------------------------------
// Finalize: reduce 4096 partials (1 block of 256), then scalar NA readout.
// ---------------------------------------------------------------------------
__global__ __launch_bounds__(BLOCK) void lc_finalize_kernel(
    const float* __restrict__ ws_partial,
    const float* __restrict__ amygdala,
    float* __restrict__ out)
{
    float s = 0.0f;
    #pragma unroll
    for (int i = 0; i < GRID / BLOCK; ++i)           // 16 strided reads/thread
        s += ws_partial[i * BLOCK + threadIdx.x];

    #pragma unroll
    for (int off = 32; off > 0; off >>= 1)
        s += __shfl_down(s, off, 64);

    __shared__ float wave_sum[BLOCK / 64];
    const int lane = threadIdx.x & 63;
    const int wid  = threadIdx.x >> 6;
    if (lane == 0) wave_sum[wid] = s;
    __syncthreads();
    if (threadIdx.x == 0) {
        float total = 0.0f;
        #pragma unroll
        for (int w = 0; w < BLOCK / 64; ++w) total += wave_sum[w];

        const float lc_mean = total / (float)N_LC;
        float raw_na = fminf(fmaxf(lc_mean * 6.0f, 0.0f), 1.0f);
        if (amygdala[0] > 0.3f) raw_na = fminf(raw_na, 0.8f);
        const float na_ema = 0.85f * 0.3f + 0.15f * raw_na;
        const float na = fminf(fmaxf(na_ema, 0.05f), 0.95f);
        out[0] = na;
        out[1] = lc_mean;
        out[2] = fminf(na * 2.0f, 1.0f);
        out[3] = fminf(na * 1.5f, 1.0f);
    }
}

extern "C" void kernel_launch(void* const* d_in, const int* in_sizes, int n_in,
                              void* d_out, int out_size, void* d_ws, size_t ws_size,
                              hipStream_t stream) {
    const float* amygdala  = (const float*)d_in[0];
    const float* insula    = (const float*)d_in[1];
    const float* circadian = (const float*)d_in[2];
    const float* cms       = (const float*)d_in[3];
    const float* v0        = (const float*)d_in[4];
    const float* u0        = (const float*)d_in[5];
    const float* rate0     = (const float*)d_in[6];
    const float* noise     = (const float*)d_in[7];
    float* out             = (float*)d_out;
    float* ws_partial      = (float*)d_ws;           // GRID floats = 16 KB

    lc_sim_kernel<<<GRID, BLOCK, 0, stream>>>(
        amygdala, insula, circadian, cms, v0, u0, rate0, noise, ws_partial);

    lc_finalize_kernel<<<1, BLOCK, 0, stream>>>(ws_partial, amygdala, out);
}